// Round 1
// baseline (5001.358 us; speedup 1.0000x reference)
//
#include <hip/hip_runtime.h>
#include <math.h>

#define T_SEQ 2048
#define DMODEL 2048
#define DLAT 1024
#define NH 16
#define DH 128
#define BATCH 2

// ---------------- RoPE tables: cos/sin [T][64] ----------------
__global__ void rope_table_kernel(float* __restrict__ cosb, float* __restrict__ sinb) {
    int idx = blockIdx.x * blockDim.x + threadIdx.x;
    if (idx >= T_SEQ * 64) return;
    int t = idx >> 6;
    int i = idx & 63;
    // inv_freq = 10000^(-2i/128)
    float inv = expf(-((2.0f * (float)i) / 128.0f) * logf(10000.0f));
    float ang = (float)t * inv;
    cosb[idx] = cosf(ang);
    sinb[idx] = sinf(ang);
}

// ---------------- fp32 tiled GEMM, 64x64 tile, BK=16, 4x4 per thread ----
// EPI: 0 = plain store to C
//      1 = RoPE epilogue (q projection), N must be 2048, cols = h*128+d
//      2 = split kv_up into K (RoPE) -> C and V -> C2; N must be 4096
template <int EPI>
__global__ __launch_bounds__(256)
void gemm64_kernel(const float* __restrict__ A, const float* __restrict__ B,
                   float* __restrict__ C, float* __restrict__ C2,
                   const float* __restrict__ cosb, const float* __restrict__ sinb,
                   int M, int N, int K) {
    __shared__ float As[16][68];   // [k][m], pad 68 -> 2-way max on r/w
    __shared__ float Bs[16][68];   // [k][n]

    const int m0 = blockIdx.y * 64;
    const int n0 = blockIdx.x * 64;
    const int tid = threadIdx.x;
    const int ty = tid >> 4;       // 0..15 -> rows ty*4..
    const int tx = tid & 15;       // 0..15 -> cols tx*4..

    float acc[4][4] = {};

    const int arow  = tid >> 2;          // 0..63
    const int acol4 = (tid & 3) * 4;     // 0,4,8,12
    const int brow  = tid >> 4;          // 0..15
    const int bcol4 = (tid & 15) * 4;

    const float* Aptr = A + (size_t)(m0 + arow) * K + acol4;
    const float* Bptr = B + (size_t)brow * N + n0 + bcol4;

    for (int k0 = 0; k0 < K; k0 += 16) {
        float4 av = *(const float4*)(Aptr + k0);
        float4 bv = *(const float4*)(Bptr + (size_t)k0 * N);
        As[acol4 + 0][arow] = av.x;
        As[acol4 + 1][arow] = av.y;
        As[acol4 + 2][arow] = av.z;
        As[acol4 + 3][arow] = av.w;
        *(float4*)&Bs[brow][bcol4] = bv;
        __syncthreads();
#pragma unroll
        for (int kk = 0; kk < 16; ++kk) {
            float4 a = *(const float4*)&As[kk][ty * 4];
            float4 b = *(const float4*)&Bs[kk][tx * 4];
            acc[0][0] += a.x * b.x; acc[0][1] += a.x * b.y; acc[0][2] += a.x * b.z; acc[0][3] += a.x * b.w;
            acc[1][0] += a.y * b.x; acc[1][1] += a.y * b.y; acc[1][2] += a.y * b.z; acc[1][3] += a.y * b.w;
            acc[2][0] += a.z * b.x; acc[2][1] += a.z * b.y; acc[2][2] += a.z * b.z; acc[2][3] += a.z * b.w;
            acc[3][0] += a.w * b.x; acc[3][1] += a.w * b.y; acc[3][2] += a.w * b.z; acc[3][3] += a.w * b.w;
        }
        __syncthreads();
    }

#pragma unroll
    for (int i = 0; i < 4; ++i) {
        const int row = m0 + ty * 4 + i;
        const int col = n0 + tx * 4;
        if (EPI == 0) {
            float4 o = { acc[i][0], acc[i][1], acc[i][2], acc[i][3] };
            *(float4*)&C[(size_t)row * N + col] = o;
        } else if (EPI == 1) {
            const int t = row & (T_SEQ - 1);
            const int d = col & 127;                 // even, pairs (d,d+1),(d+2,d+3)
            const float c0 = cosb[t * 64 + (d >> 1)];
            const float s0 = sinb[t * 64 + (d >> 1)];
            const float c1 = cosb[t * 64 + ((d + 2) >> 1)];
            const float s1 = sinb[t * 64 + ((d + 2) >> 1)];
            float4 o;
            o.x = acc[i][0] * c0 - acc[i][1] * s0;
            o.y = acc[i][0] * s0 + acc[i][1] * c0;
            o.z = acc[i][2] * c1 - acc[i][3] * s1;
            o.w = acc[i][2] * s1 + acc[i][3] * c1;
            *(float4*)&C[(size_t)row * N + col] = o;
        } else { // EPI == 2
            const int t  = row & (T_SEQ - 1);
            const int h  = col >> 8;     // head (N=4096, 256 per head)
            const int hn = col & 255;
            if (hn < 128) {              // K half -> RoPE -> C (k buffer, [4096][2048])
                const int d = hn;
                const float c0 = cosb[t * 64 + (d >> 1)];
                const float s0 = sinb[t * 64 + (d >> 1)];
                const float c1 = cosb[t * 64 + ((d + 2) >> 1)];
                const float s1 = sinb[t * 64 + ((d + 2) >> 1)];
                float4 o;
                o.x = acc[i][0] * c0 - acc[i][1] * s0;
                o.y = acc[i][0] * s0 + acc[i][1] * c0;
                o.z = acc[i][2] * c1 - acc[i][3] * s1;
                o.w = acc[i][2] * s1 + acc[i][3] * c1;
                *(float4*)&C[(size_t)row * DMODEL + h * DH + d] = o;
            } else {                     // V half -> C2 (v buffer, [4096][2048])
                float4 o = { acc[i][0], acc[i][1], acc[i][2], acc[i][3] };
                *(float4*)&C2[(size_t)row * DMODEL + h * DH + (hn - 128)] = o;
            }
        }
    }
}

// ---------------- causal flash attention, fp32 ----------------
// grid: (T/64, B*NH), block 256. 64 queries/block, 4 lanes per query row,
// each lane owns 32 of the 128 dims. K/V tiles of 32 keys staged in LDS.
#define QB 64
#define KB 32
__global__ __launch_bounds__(256)
void attn_kernel(const float* __restrict__ Q, const float* __restrict__ Kb,
                 const float* __restrict__ Vb, float* __restrict__ O) {
    const int bh = blockIdx.y;
    const int b  = bh >> 4;
    const int h  = bh & 15;
    const int q0 = blockIdx.x * QB;
    const int tid  = threadIdx.x;
    const int ql   = tid >> 2;   // 0..63
    const int part = tid & 3;    // 0..3 -> dims part*32..
    const int qrow = q0 + ql;
    const float scale = 0.08838834764831845f;  // 1/sqrt(128)

    __shared__ float Ks[KB][DH];
    __shared__ float Vs[KB][DH];

    // q slice into registers
    float qreg[32];
    const float* qptr = Q + ((size_t)(b * T_SEQ + qrow)) * DMODEL + h * DH + part * 32;
#pragma unroll
    for (int i = 0; i < 8; ++i) {
        float4 v = *(const float4*)(qptr + i * 4);
        qreg[i * 4 + 0] = v.x; qreg[i * 4 + 1] = v.y;
        qreg[i * 4 + 2] = v.z; qreg[i * 4 + 3] = v.w;
    }

    float acc[32];
#pragma unroll
    for (int d = 0; d < 32; ++d) acc[d] = 0.f;
    float m = -INFINITY, l = 0.f;

    const int nkt = (q0 + QB) / KB;   // causal: tiles with k0 < q0+QB
    for (int kt = 0; kt < nkt; ++kt) {
        const int k0 = kt * KB;
        __syncthreads();   // protect previous tile reads
#pragma unroll
        for (int i = 0; i < 4; ++i) {
            int idx = tid + i * 256;          // float4 index 0..1023
            int kr  = idx >> 5;               // key row 0..31
            int cc  = (idx & 31) * 4;         // col 0..124
            size_t gro = ((size_t)(b * T_SEQ + k0 + kr)) * DMODEL + h * DH + cc;
            *(float4*)&Ks[kr][cc] = *(const float4*)(Kb + gro);
            *(float4*)&Vs[kr][cc] = *(const float4*)(Vb + gro);
        }
        __syncthreads();

#pragma unroll 4
        for (int j = 0; j < KB; ++j) {
            const int kk = k0 + j;
            float s = 0.f;
#pragma unroll
            for (int d = 0; d < 32; ++d) s += qreg[d] * Ks[j][part * 32 + d];
            s += __shfl_xor(s, 1);
            s += __shfl_xor(s, 2);
            s = (kk <= qrow) ? s * scale : -INFINITY;
            const float mn    = fmaxf(m, s);
            const float alpha = __expf(m - mn);   // m=-inf first key -> 0
            const float p     = __expf(s - mn);   // s=-inf masked   -> 0
            m = mn;
            l = l * alpha + p;
#pragma unroll
            for (int d = 0; d < 32; ++d)
                acc[d] = acc[d] * alpha + p * Vs[j][part * 32 + d];
        }
    }

    const float inv_l = 1.f / l;
    float* optr = O + ((size_t)(b * T_SEQ + qrow)) * DMODEL + h * DH + part * 32;
#pragma unroll
    for (int i = 0; i < 8; ++i) {
        float4 v;
        v.x = acc[i * 4 + 0] * inv_l; v.y = acc[i * 4 + 1] * inv_l;
        v.z = acc[i * 4 + 2] * inv_l; v.w = acc[i * 4 + 3] * inv_l;
        *(float4*)(optr + i * 4) = v;
    }
}

extern "C" void kernel_launch(void* const* d_in, const int* in_sizes, int n_in,
                              void* d_out, int out_size, void* d_ws, size_t ws_size,
                              hipStream_t stream) {
    const float* x      = (const float*)d_in[0];  // [B,T,D]
    const float* wq     = (const float*)d_in[1];  // [D, 2048]
    const float* w_down = (const float*)d_in[2];  // [D, 1024]
    const float* w_up   = (const float*)d_in[3];  // [1024, 4096]
    const float* wo     = (const float*)d_in[4];  // [2048, 2048]
    float* out = (float*)d_out;                   // [B,T,D]

    float* ws   = (float*)d_ws;
    float* cosb = ws;                              // 2048*64
    float* sinb = cosb + T_SEQ * 64;
    float* qbuf = sinb + T_SEQ * 64;               // 4096*2048
    float* ckv  = qbuf + (size_t)BATCH * T_SEQ * DMODEL;   // 4096*1024
    float* kbuf = ckv  + (size_t)BATCH * T_SEQ * DLAT;     // 4096*2048
    float* vbuf = kbuf + (size_t)BATCH * T_SEQ * DMODEL;   // 4096*2048
    float* abuf = vbuf + (size_t)BATCH * T_SEQ * DMODEL;   // 4096*2048

    const int M = BATCH * T_SEQ;   // 4096

    // 1. RoPE tables
    rope_table_kernel<<<(T_SEQ * 64 + 255) / 256, 256, 0, stream>>>(cosb, sinb);

    // 2. q = rope(x @ wq)
    gemm64_kernel<1><<<dim3(DMODEL / 64, M / 64), 256, 0, stream>>>(
        x, wq, qbuf, nullptr, cosb, sinb, M, DMODEL, DMODEL);

    // 3. c_kv = x @ w_down
    gemm64_kernel<0><<<dim3(DLAT / 64, M / 64), 256, 0, stream>>>(
        x, w_down, ckv, nullptr, nullptr, nullptr, M, DLAT, DMODEL);

    // 4. kv_up = c_kv @ w_up -> k (rope), v
    gemm64_kernel<2><<<dim3((2 * NH * DH) / 64, M / 64), 256, 0, stream>>>(
        ckv, w_up, kbuf, vbuf, cosb, sinb, M, 2 * NH * DH, DLAT);

    // 5. causal attention
    attn_kernel<<<dim3(T_SEQ / QB, BATCH * NH), 256, 0, stream>>>(qbuf, kbuf, vbuf, abuf);

    // 6. out = attn @ wo
    gemm64_kernel<0><<<dim3(DMODEL / 64, M / 64), 256, 0, stream>>>(
        abuf, wo, out, nullptr, nullptr, nullptr, M, DMODEL, DMODEL);
}

// Round 2
// 828.754 us; speedup vs baseline: 6.0348x; 6.0348x over previous
//
#include <hip/hip_runtime.h>
#include <math.h>
#include <stdint.h>

#define T_SEQ 2048
#define DMODEL 2048
#define DLAT 1024
#define NH 16
#define DH 128
#define BATCH 2
#define MTOT (BATCH * T_SEQ)   // 4096 rows total

typedef float f32x4 __attribute__((ext_vector_type(4)));
typedef __bf16 bf16x8 __attribute__((ext_vector_type(8)));

__device__ __forceinline__ unsigned short f2bf(float f) {
    union { float f; unsigned u; } v; v.f = f;
    unsigned r = (v.u + 0x7fffu + ((v.u >> 16) & 1u)) >> 16;   // RNE
    return (unsigned short)r;
}

// async global->LDS, 16B per lane (dest must be linear: wave base + lane*16)
#define GLL16(g, l) __builtin_amdgcn_global_load_lds( \
    (const __attribute__((address_space(1))) unsigned int*)(g), \
    (__attribute__((address_space(3))) unsigned int*)(l), 16, 0, 0)

// ---------------- RoPE tables: cos/sin [T][64] fp32 ----------------
__global__ void rope_table_kernel(float* __restrict__ cosb, float* __restrict__ sinb) {
    int idx = blockIdx.x * blockDim.x + threadIdx.x;
    if (idx >= T_SEQ * 64) return;
    int t = idx >> 6;
    int i = idx & 63;
    float inv = expf(-((2.0f * (float)i) / 128.0f) * logf(10000.0f));
    float ang = (float)t * inv;
    cosb[idx] = cosf(ang);
    sinb[idx] = sinf(ang);
}

// ---------------- fp32 -> bf16 elementwise (x) ----------------
__global__ void conv_f2b_kernel(const float* __restrict__ s, unsigned short* __restrict__ d) {
    int i = (blockIdx.x * blockDim.x + threadIdx.x) * 4;
    float4 v = *(const float4*)(s + i);
    ushort4 o;
    o.x = f2bf(v.x); o.y = f2bf(v.y); o.z = f2bf(v.z); o.w = f2bf(v.w);
    *(ushort4*)(d + i) = o;
}

// ---------------- fp32 [R][C] -> bf16 [C][R] transpose ----------------
__global__ void transpose_f2b_kernel(const float* __restrict__ src, unsigned short* __restrict__ dst,
                                     int R, int C) {
    __shared__ unsigned short tile[32][33];
    int tx = threadIdx.x & 31, ty = threadIdx.x >> 5;   // 32 x 8
    int r0 = blockIdx.y * 32, c0 = blockIdx.x * 32;
#pragma unroll
    for (int i = 0; i < 32; i += 8)
        tile[ty + i][tx] = f2bf(src[(size_t)(r0 + ty + i) * C + c0 + tx]);
    __syncthreads();
#pragma unroll
    for (int i = 0; i < 32; i += 8)
        dst[(size_t)(c0 + ty + i) * R + r0 + tx] = tile[tx][ty + i];
}

// ---------------- bf16 [R][C] -> bf16 [C][R] transpose (V -> V^T) ----------------
__global__ void transpose_b2b_kernel(const unsigned short* __restrict__ src, unsigned short* __restrict__ dst,
                                     int R, int C) {
    __shared__ unsigned short tile[32][33];
    int tx = threadIdx.x & 31, ty = threadIdx.x >> 5;
    int r0 = blockIdx.y * 32, c0 = blockIdx.x * 32;
#pragma unroll
    for (int i = 0; i < 32; i += 8)
        tile[ty + i][tx] = src[(size_t)(r0 + ty + i) * C + c0 + tx];
    __syncthreads();
#pragma unroll
    for (int i = 0; i < 32; i += 8)
        dst[(size_t)(c0 + ty + i) * R + r0 + tx] = tile[tx][ty + i];
}

// ---------------- bf16 MFMA GEMM: C[M,N] = A[M,K] * BT[N,K]^T ----------------
// 128x128 tile, BK=32, 256 thr (4 waves 2x2), wave = 64x64 = 4x4 frags of 16x16x32.
// EPI: 0 = bf16 store, 1 = bf16 store + RoPE (q), 2 = K(RoPE)/V split bf16, 3 = fp32 store
template <int EPI>
__global__ __launch_bounds__(256)
void gemm_bf16_kernel(const unsigned short* __restrict__ A, const unsigned short* __restrict__ BT,
                      void* __restrict__ C0, void* __restrict__ C1,
                      const float* __restrict__ cosb, const float* __restrict__ sinb,
                      int M, int N, int K) {
    __shared__ unsigned short As[128 * 32];
    __shared__ unsigned short Bs[128 * 32];
    const int t = threadIdx.x;
    const int w = t >> 6, l = t & 63;
    const int wr = w >> 1, wc = w & 1;
    const int lr = l & 15, lg = l >> 4;
    const int m0 = blockIdx.y * 128, n0 = blockIdx.x * 128;

    f32x4 acc[4][4] = {{}};

    const unsigned short* aP  = A  + (size_t)(m0 + (t >> 2)) * K + (t & 3) * 8;
    const unsigned short* aP2 = aP + (size_t)64 * K;
    const unsigned short* bP  = BT + (size_t)(n0 + (t >> 2)) * K + (t & 3) * 8;
    const unsigned short* bP2 = bP + (size_t)64 * K;

    for (int k0 = 0; k0 < K; k0 += 32) {
        __syncthreads();                       // protect previous iteration's reads
        GLL16(aP  + k0, &As[t * 8]);
        GLL16(aP2 + k0, &As[2048 + t * 8]);
        GLL16(bP  + k0, &Bs[t * 8]);
        GLL16(bP2 + k0, &Bs[2048 + t * 8]);
        __syncthreads();                       // drains vmcnt (loads landed)

        bf16x8 af[4], bfr[4];
#pragma unroll
        for (int i = 0; i < 4; ++i)
            af[i] = *(const bf16x8*)&As[(wr * 64 + i * 16 + lr) * 32 + lg * 8];
#pragma unroll
        for (int j = 0; j < 4; ++j)
            bfr[j] = *(const bf16x8*)&Bs[(wc * 64 + j * 16 + lr) * 32 + lg * 8];
#pragma unroll
        for (int i = 0; i < 4; ++i)
#pragma unroll
            for (int j = 0; j < 4; ++j)
                acc[i][j] = __builtin_amdgcn_mfma_f32_16x16x32_bf16(af[i], bfr[j], acc[i][j], 0, 0, 0);
    }

    const bool is_v = (EPI == 2) && ((n0 & 128) != 0);   // block-uniform
#pragma unroll
    for (int i = 0; i < 4; ++i) {
#pragma unroll
        for (int j = 0; j < 4; ++j) {
#pragma unroll
            for (int rr = 0; rr < 4; ++rr) {
                const int row_g = m0 + wr * 64 + i * 16 + lg * 4 + rr;
                const int col_g = n0 + wc * 64 + j * 16 + lr;
                float v = acc[i][j][rr];
                if (EPI == 0) {
                    ((unsigned short*)C0)[(size_t)row_g * N + col_g] = f2bf(v);
                } else if (EPI == 1) {
                    float o_ = __shfl_xor(v, 1);
                    int d = col_g & 127;
                    int tp = row_g & (T_SEQ - 1);
                    float c = cosb[tp * 64 + (d >> 1)];
                    float s = sinb[tp * 64 + (d >> 1)];
                    float res = (lr & 1) ? (o_ * s + v * c) : (v * c - o_ * s);
                    ((unsigned short*)C0)[(size_t)row_g * N + col_g] = f2bf(res);
                } else if (EPI == 2) {
                    float res = v;
                    if (!is_v) {  // K half -> RoPE
                        float o_ = __shfl_xor(v, 1);
                        int d = col_g & 127;
                        int tp = row_g & (T_SEQ - 1);
                        float c = cosb[tp * 64 + (d >> 1)];
                        float s = sinb[tp * 64 + (d >> 1)];
                        res = (lr & 1) ? (o_ * s + v * c) : (v * c - o_ * s);
                    }
                    int dcol = ((col_g >> 8) << 7) | (col_g & 127);  // head*128 + d
                    unsigned short* dst = is_v ? (unsigned short*)C1 : (unsigned short*)C0;
                    dst[(size_t)row_g * DMODEL + dcol] = f2bf(res);
                } else {  // EPI == 3, fp32 final
                    ((float*)C0)[(size_t)row_g * N + col_g] = v;
                }
            }
        }
    }
}

// ---------------- bf16 MFMA causal flash attention ----------------
// grid (T/64, B*NH), 256 thr = 4 indep waves; wave = 16 q rows, 32-key tiles.
// Q,K row-major bf16 [4096][2048] (head-blocked); V^T bf16 [2048][4096].
__global__ __launch_bounds__(256)
void attn_mfma_kernel(const unsigned short* __restrict__ qb, const unsigned short* __restrict__ kb,
                      const unsigned short* __restrict__ vT, unsigned short* __restrict__ ob) {
    const int bh = blockIdx.y;
    const int b = bh >> 4, h = bh & 15;
    const int w = threadIdx.x >> 6;
    const int l = threadIdx.x & 63;
    const int lr = l & 15, lg = l >> 4;
    const int q_base = blockIdx.x * 64 + w * 16;

    __shared__ unsigned short Ps[4][16][40];   // per-wave P relayout buffer

    // Q frags (4 d-chunks of 32), resident whole kernel
    bf16x8 qf[4];
    const unsigned short* qrow = qb + (size_t)(b * T_SEQ + q_base + lr) * DMODEL + h * DH;
#pragma unroll
    for (int c = 0; c < 4; ++c)
        qf[c] = *(const bf16x8*)(qrow + c * 32 + lg * 8);

    f32x4 o[8] = {};
    float m[4], lsum[4];
#pragma unroll
    for (int r = 0; r < 4; ++r) { m[r] = -3.0e38f; lsum[r] = 0.f; }

    const unsigned short* kbase = kb + (size_t)(b * T_SEQ) * DMODEL + h * DH;
    const float sc = 0.08838834764831845f;     // 1/sqrt(128)
    const int ntiles = ((q_base + 15) >> 5) + 1;

    for (int kt = 0; kt < ntiles; ++kt) {
        const int k0 = kt * 32;
        // ---- S = Q K^T (two 16-key halves) ----
        f32x4 s0 = {0.f, 0.f, 0.f, 0.f}, s1 = {0.f, 0.f, 0.f, 0.f};
        const unsigned short* kr0 = kbase + (size_t)(k0 + lr) * DMODEL;
        const unsigned short* kr1 = kbase + (size_t)(k0 + 16 + lr) * DMODEL;
        bf16x8 kf0[4], kf1[4];
#pragma unroll
        for (int c = 0; c < 4; ++c) {
            kf0[c] = *(const bf16x8*)(kr0 + c * 32 + lg * 8);
            kf1[c] = *(const bf16x8*)(kr1 + c * 32 + lg * 8);
        }
#pragma unroll
        for (int c = 0; c < 4; ++c) {
            s0 = __builtin_amdgcn_mfma_f32_16x16x32_bf16(qf[c], kf0[c], s0, 0, 0, 0);
            s1 = __builtin_amdgcn_mfma_f32_16x16x32_bf16(qf[c], kf1[c], s1, 0, 0, 0);
        }
        // ---- scale + causal mask ----
#pragma unroll
        for (int r = 0; r < 4; ++r) { s0[r] *= sc; s1[r] *= sc; }
        if (k0 + 31 > q_base) {
#pragma unroll
            for (int r = 0; r < 4; ++r) {
                int row = q_base + lg * 4 + r;
                if (k0 + lr > row)      s0[r] = -3.0e38f;
                if (k0 + 16 + lr > row) s1[r] = -3.0e38f;
            }
        }
        // ---- online softmax (tile-level) ----
        float alpha[4];
#pragma unroll
        for (int r = 0; r < 4; ++r) {
            float t = fmaxf(s0[r], s1[r]);
            t = fmaxf(t, __shfl_xor(t, 1)); t = fmaxf(t, __shfl_xor(t, 2));
            t = fmaxf(t, __shfl_xor(t, 4)); t = fmaxf(t, __shfl_xor(t, 8));
            float mn = fmaxf(m[r], t);
            alpha[r] = __expf(m[r] - mn);
            m[r] = mn;
            s0[r] = __expf(s0[r] - mn);
            s1[r] = __expf(s1[r] - mn);
            float rs = s0[r] + s1[r];
            rs += __shfl_xor(rs, 1); rs += __shfl_xor(rs, 2);
            rs += __shfl_xor(rs, 4); rs += __shfl_xor(rs, 8);
            lsum[r] = lsum[r] * alpha[r] + rs;
        }
#pragma unroll
        for (int i = 0; i < 8; ++i)
#pragma unroll
            for (int r = 0; r < 4; ++r) o[i][r] *= alpha[r];
        // ---- P -> bf16, relayout via per-wave LDS (same-wave, no barrier) ----
#pragma unroll
        for (int r = 0; r < 4; ++r) {
            Ps[w][lg * 4 + r][lr]      = f2bf(s0[r]);
            Ps[w][lg * 4 + r][16 + lr] = f2bf(s1[r]);
        }
        bf16x8 pa = *(const bf16x8*)&Ps[w][lr][lg * 8];
        // ---- O += P V ----
#pragma unroll
        for (int i = 0; i < 8; ++i) {
            const unsigned short* vp = vT + (size_t)(h * DH + i * 16 + lr) * MTOT + b * T_SEQ + k0 + lg * 8;
            bf16x8 vf = *(const bf16x8*)vp;
            o[i] = __builtin_amdgcn_mfma_f32_16x16x32_bf16(pa, vf, o[i], 0, 0, 0);
        }
    }

    // ---- epilogue: O/l -> bf16 attn-out [4096][2048] ----
#pragma unroll
    for (int i = 0; i < 8; ++i) {
#pragma unroll
        for (int r = 0; r < 4; ++r) {
            float v = o[i][r] / lsum[r];
            ob[(size_t)(b * T_SEQ + q_base + lg * 4 + r) * DMODEL + h * DH + i * 16 + lr] = f2bf(v);
        }
    }
}

extern "C" void kernel_launch(void* const* d_in, const int* in_sizes, int n_in,
                              void* d_out, int out_size, void* d_ws, size_t ws_size,
                              hipStream_t stream) {
    const float* x      = (const float*)d_in[0];  // [4096, 2048]
    const float* wq     = (const float*)d_in[1];  // [2048, 2048]
    const float* w_down = (const float*)d_in[2];  // [2048, 1024]
    const float* w_up   = (const float*)d_in[3];  // [1024, 4096]
    const float* wo     = (const float*)d_in[4];  // [2048, 2048]
    float* out = (float*)d_out;

    uint8_t* p = (uint8_t*)d_ws;
    float* cosb = (float*)p;            p += (size_t)T_SEQ * 64 * 4;
    float* sinb = (float*)p;            p += (size_t)T_SEQ * 64 * 4;
    unsigned short* xb   = (unsigned short*)p; p += (size_t)MTOT * DMODEL * 2;
    unsigned short* wqT  = (unsigned short*)p; p += (size_t)DMODEL * DMODEL * 2;
    unsigned short* wdT  = (unsigned short*)p; p += (size_t)DLAT * DMODEL * 2;
    unsigned short* wuT  = (unsigned short*)p; p += (size_t)(2 * NH * DH) * DLAT * 2;
    unsigned short* woT  = (unsigned short*)p; p += (size_t)DMODEL * DMODEL * 2;
    unsigned short* qbuf = (unsigned short*)p; p += (size_t)MTOT * DMODEL * 2;
    unsigned short* ckv  = (unsigned short*)p; p += (size_t)MTOT * DLAT * 2;
    unsigned short* kbuf = (unsigned short*)p; p += (size_t)MTOT * DMODEL * 2;
    unsigned short* vbuf = (unsigned short*)p; p += (size_t)MTOT * DMODEL * 2;
    unsigned short* vT   = (unsigned short*)p; p += (size_t)DMODEL * MTOT * 2;
    unsigned short* abuf = xb;   // alias: xb dead after GEMM2, abuf written after

    // prep: tables + conversions/transposes
    rope_table_kernel<<<(T_SEQ * 64) / 256, 256, 0, stream>>>(cosb, sinb);
    conv_f2b_kernel<<<(MTOT * DMODEL / 4) / 256, 256, 0, stream>>>(x, xb);
    transpose_f2b_kernel<<<dim3(DMODEL / 32, DMODEL / 32), 256, 0, stream>>>(wq, wqT, DMODEL, DMODEL);
    transpose_f2b_kernel<<<dim3(DLAT / 32, DMODEL / 32), 256, 0, stream>>>(w_down, wdT, DMODEL, DLAT);
    transpose_f2b_kernel<<<dim3((2 * NH * DH) / 32, DLAT / 32), 256, 0, stream>>>(w_up, wuT, DLAT, 2 * NH * DH);
    transpose_f2b_kernel<<<dim3(DMODEL / 32, DMODEL / 32), 256, 0, stream>>>(wo, woT, DMODEL, DMODEL);

    // q = rope(x @ wq)
    gemm_bf16_kernel<1><<<dim3(DMODEL / 128, MTOT / 128), 256, 0, stream>>>(
        xb, wqT, qbuf, nullptr, cosb, sinb, MTOT, DMODEL, DMODEL);
    // c_kv = x @ w_down
    gemm_bf16_kernel<0><<<dim3(DLAT / 128, MTOT / 128), 256, 0, stream>>>(
        xb, wdT, ckv, nullptr, cosb, sinb, MTOT, DLAT, DMODEL);
    // kv_up = c_kv @ w_up -> k (rope) / v
    gemm_bf16_kernel<2><<<dim3((2 * NH * DH) / 128, MTOT / 128), 256, 0, stream>>>(
        ckv, wuT, kbuf, vbuf, cosb, sinb, MTOT, 2 * NH * DH, DLAT);
    // v -> v^T
    transpose_b2b_kernel<<<dim3(DMODEL / 32, MTOT / 32), 256, 0, stream>>>(vbuf, vT, MTOT, DMODEL);
    // attention
    attn_mfma_kernel<<<dim3(T_SEQ / 64, BATCH * NH), 256, 0, stream>>>(qbuf, kbuf, vT, abuf);
    // out = attn @ wo (fp32)
    gemm_bf16_kernel<3><<<dim3(DMODEL / 128, MTOT / 128), 256, 0, stream>>>(
        abuf, woT, out, nullptr, cosb, sinb, MTOT, DMODEL, DMODEL);
}

// Round 3
// 508.308 us; speedup vs baseline: 9.8392x; 1.6304x over previous
//
#include <hip/hip_runtime.h>
#include <math.h>
#include <stdint.h>

#define T_SEQ 2048
#define DMODEL 2048
#define DLAT 1024
#define NH 16
#define DH 128
#define BATCH 2
#define MTOT (BATCH * T_SEQ)   // 4096 rows total

typedef float f32x4 __attribute__((ext_vector_type(4)));
typedef __bf16 bf16x8 __attribute__((ext_vector_type(8)));

__device__ __forceinline__ unsigned short f2bf(float f) {
    union { float f; unsigned u; } v; v.f = f;
    unsigned r = (v.u + 0x7fffu + ((v.u >> 16) & 1u)) >> 16;   // RNE
    return (unsigned short)r;
}

// async global->LDS, 16B per lane (dest must be linear: wave base + lane*16)
#define GLL16(g, l) __builtin_amdgcn_global_load_lds( \
    (const __attribute__((address_space(1))) unsigned int*)(g), \
    (__attribute__((address_space(3))) unsigned int*)(l), 16, 0, 0)

// ---------------- RoPE tables: cos/sin [T][64] fp32 ----------------
__global__ void rope_table_kernel(float* __restrict__ cosb, float* __restrict__ sinb) {
    int idx = blockIdx.x * blockDim.x + threadIdx.x;
    if (idx >= T_SEQ * 64) return;
    int t = idx >> 6;
    int i = idx & 63;
    float inv = expf(-((2.0f * (float)i) / 128.0f) * logf(10000.0f));
    float ang = (float)t * inv;
    cosb[idx] = cosf(ang);
    sinb[idx] = sinf(ang);
}

// ---------------- fp32 -> bf16 elementwise (x) ----------------
__global__ void conv_f2b_kernel(const float* __restrict__ s, unsigned short* __restrict__ d) {
    int i = (blockIdx.x * blockDim.x + threadIdx.x) * 4;
    float4 v = *(const float4*)(s + i);
    ushort4 o;
    o.x = f2bf(v.x); o.y = f2bf(v.y); o.z = f2bf(v.z); o.w = f2bf(v.w);
    *(ushort4*)(d + i) = o;
}

// ---------------- fp32 [R][C] -> bf16 [C][R] transpose ----------------
__global__ void transpose_f2b_kernel(const float* __restrict__ src, unsigned short* __restrict__ dst,
                                     int R, int C) {
    __shared__ unsigned short tile[32][33];
    int tx = threadIdx.x & 31, ty = threadIdx.x >> 5;   // 32 x 8
    int r0 = blockIdx.y * 32, c0 = blockIdx.x * 32;
#pragma unroll
    for (int i = 0; i < 32; i += 8)
        tile[ty + i][tx] = f2bf(src[(size_t)(r0 + ty + i) * C + c0 + tx]);
    __syncthreads();
#pragma unroll
    for (int i = 0; i < 32; i += 8)
        dst[(size_t)(c0 + ty + i) * R + r0 + tx] = tile[tx][ty + i];
}

// ---------------- bf16 [R][C] -> bf16 [C][R] transpose (V -> V^T) ----------------
__global__ void transpose_b2b_kernel(const unsigned short* __restrict__ src, unsigned short* __restrict__ dst,
                                     int R, int C) {
    __shared__ unsigned short tile[32][33];
    int tx = threadIdx.x & 31, ty = threadIdx.x >> 5;
    int r0 = blockIdx.y * 32, c0 = blockIdx.x * 32;
#pragma unroll
    for (int i = 0; i < 32; i += 8)
        tile[ty + i][tx] = src[(size_t)(r0 + ty + i) * C + c0 + tx];
    __syncthreads();
#pragma unroll
    for (int i = 0; i < 32; i += 8)
        dst[(size_t)(c0 + ty + i) * R + r0 + tx] = tile[tx][ty + i];
}

// ---------------- bf16 MFMA GEMM: C[M,N] = A[M,K] * BT[N,K]^T ----------------
// 128x128 tile, BK=32, 256 thr (4 waves 2x2), wave = 64x64 = 4x4 frags of 16x16x32.
// EPI: 0 = bf16 store, 1 = bf16 store + RoPE (q), 2 = K(RoPE)/V split bf16, 3 = fp32 store
template <int EPI>
__global__ __launch_bounds__(256)
void gemm_bf16_kernel(const unsigned short* __restrict__ A, const unsigned short* __restrict__ BT,
                      void* __restrict__ C0, void* __restrict__ C1,
                      const float* __restrict__ cosb, const float* __restrict__ sinb,
                      int M, int N, int K) {
    __shared__ unsigned short As[128 * 32];
    __shared__ unsigned short Bs[128 * 32];
    const int t = threadIdx.x;
    const int w = t >> 6, l = t & 63;
    const int wr = w >> 1, wc = w & 1;
    const int lr = l & 15, lg = l >> 4;
    const int m0 = blockIdx.y * 128, n0 = blockIdx.x * 128;

    f32x4 acc[4][4] = {{}};

    const unsigned short* aP  = A  + (size_t)(m0 + (t >> 2)) * K + (t & 3) * 8;
    const unsigned short* aP2 = aP + (size_t)64 * K;
    const unsigned short* bP  = BT + (size_t)(n0 + (t >> 2)) * K + (t & 3) * 8;
    const unsigned short* bP2 = bP + (size_t)64 * K;

    for (int k0 = 0; k0 < K; k0 += 32) {
        __syncthreads();                       // protect previous iteration's reads
        GLL16(aP  + k0, &As[t * 8]);
        GLL16(aP2 + k0, &As[2048 + t * 8]);
        GLL16(bP  + k0, &Bs[t * 8]);
        GLL16(bP2 + k0, &Bs[2048 + t * 8]);
        __syncthreads();                       // drains vmcnt (loads landed)

        bf16x8 af[4], bfr[4];
#pragma unroll
        for (int i = 0; i < 4; ++i)
            af[i] = *(const bf16x8*)&As[(wr * 64 + i * 16 + lr) * 32 + lg * 8];
#pragma unroll
        for (int j = 0; j < 4; ++j)
            bfr[j] = *(const bf16x8*)&Bs[(wc * 64 + j * 16 + lr) * 32 + lg * 8];
#pragma unroll
        for (int i = 0; i < 4; ++i)
#pragma unroll
            for (int j = 0; j < 4; ++j)
                acc[i][j] = __builtin_amdgcn_mfma_f32_16x16x32_bf16(af[i], bfr[j], acc[i][j], 0, 0, 0);
    }

    const bool is_v = (EPI == 2) && ((n0 & 128) != 0);   // block-uniform
#pragma unroll
    for (int i = 0; i < 4; ++i) {
#pragma unroll
        for (int j = 0; j < 4; ++j) {
#pragma unroll
            for (int rr = 0; rr < 4; ++rr) {
                const int row_g = m0 + wr * 64 + i * 16 + lg * 4 + rr;
                const int col_g = n0 + wc * 64 + j * 16 + lr;
                float v = acc[i][j][rr];
                if (EPI == 0) {
                    ((unsigned short*)C0)[(size_t)row_g * N + col_g] = f2bf(v);
                } else if (EPI == 1) {
                    float o_ = __shfl_xor(v, 1);
                    int d = col_g & 127;
                    int tp = row_g & (T_SEQ - 1);
                    float c = cosb[tp * 64 + (d >> 1)];
                    float s = sinb[tp * 64 + (d >> 1)];
                    float res = (lr & 1) ? (o_ * s + v * c) : (v * c - o_ * s);
                    ((unsigned short*)C0)[(size_t)row_g * N + col_g] = f2bf(res);
                } else if (EPI == 2) {
                    float res = v;
                    if (!is_v) {  // K half -> RoPE
                        float o_ = __shfl_xor(v, 1);
                        int d = col_g & 127;
                        int tp = row_g & (T_SEQ - 1);
                        float c = cosb[tp * 64 + (d >> 1)];
                        float s = sinb[tp * 64 + (d >> 1)];
                        res = (lr & 1) ? (o_ * s + v * c) : (v * c - o_ * s);
                    }
                    int dcol = ((col_g >> 8) << 7) | (col_g & 127);  // head*128 + d
                    unsigned short* dst = is_v ? (unsigned short*)C1 : (unsigned short*)C0;
                    dst[(size_t)row_g * DMODEL + dcol] = f2bf(res);
                } else {  // EPI == 3, fp32 final
                    ((float*)C0)[(size_t)row_g * N + col_g] = v;
                }
            }
        }
    }
}

// ---------------- staged bf16 MFMA causal flash attention ----------------
// grid (B*NH, 16), 256 thr = 4 waves. Block: 128 q-rows (wave w: rows w*32, two
// 16-row frags). KV tiles of 64 keys: K double-buffered LDS, V^T single (staged
// at iter top, consumed after mid-iter barrier). XOR-swizzled LDS via
// pre-swizzled global_load_lds source. LPT: qt = 15 - blockIdx.y.
__global__ __launch_bounds__(256, 2)
void attn_mfma2_kernel(const unsigned short* __restrict__ qb, const unsigned short* __restrict__ kb,
                       const unsigned short* __restrict__ vT, unsigned short* __restrict__ ob) {
    __shared__ __align__(16) unsigned short Ks[2][64 * 128];   // 2 x 16KB
    __shared__ __align__(16) unsigned short Vs[128 * 64];      // 16KB (V^T: d-major)
    __shared__ __align__(16) unsigned short Ps[4][16][64];     // 8KB, per-wave P buf

    const int bh = blockIdx.x;
    const int b = bh >> 4, h = bh & 15;
    const int qt = 15 - blockIdx.y;           // longest blocks first
    const int t = threadIdx.x;
    const int w = t >> 6, l = t & 63;
    const int lr = l & 15, lg = l >> 4;

    const unsigned short* kbase = kb + (size_t)(b * T_SEQ) * DMODEL + h * DH;
    const unsigned short* vbase = vT + (size_t)(h * DH) * MTOT + (size_t)b * T_SEQ;
    const float sc = 0.08838834764831845f;    // 1/sqrt(128)

    const int q0 = qt * 128;
    const int q_base = q0 + w * 32;

    // Q frags: rg in {0,1}, rows q_base + rg*16 + lr
    bf16x8 qf[2][4];
#pragma unroll
    for (int rg = 0; rg < 2; ++rg) {
        const unsigned short* qrow = qb + (size_t)(b * T_SEQ + q_base + rg * 16 + lr) * DMODEL + h * DH;
#pragma unroll
        for (int c = 0; c < 4; ++c) qf[rg][c] = *(const bf16x8*)(qrow + c * 32 + lg * 8);
    }

    f32x4 o[2][8] = {{}};
    float m[2][4], lsum[2][4];
#pragma unroll
    for (int rg = 0; rg < 2; ++rg)
#pragma unroll
        for (int r = 0; r < 4; ++r) { m[rg][r] = -3.0e38f; lsum[rg][r] = 0.f; }

    const int nt = 2 * qt + 2;
    int cur = 0;

    // prologue: stage K tile 0 into Ks[0] (src pre-swizzled, LDS dest linear)
#pragma unroll
    for (int i = 0; i < 4; ++i) {
        int c = i * 256 + t;                  // 16B chunk 0..1023
        int row = c >> 4;                     // 0..63
        int k16 = (c & 15) ^ (row & 7);
        GLL16(kbase + (size_t)row * DMODEL + k16 * 8, &Ks[0][c * 8]);
    }
    __syncthreads();

    for (int kt = 0; kt < nt; ++kt) {
        const int k0 = kt * 64;
        // prefetch next K tile into other buffer
        if (kt + 1 < nt) {
            const int kn = k0 + 64;
#pragma unroll
            for (int i = 0; i < 4; ++i) {
                int c = i * 256 + t;
                int row = c >> 4;
                int k16 = (c & 15) ^ (row & 7);
                GLL16(kbase + (size_t)(kn + row) * DMODEL + k16 * 8, &Ks[cur ^ 1][c * 8]);
            }
        }
        // stage current V^T tile (consumed after barrier 1)
#pragma unroll
        for (int i = 0; i < 4; ++i) {
            int c = i * 256 + t;              // 0..1023
            int d = c >> 3;                   // 0..127
            int k8 = (c & 7) ^ (d & 7);
            GLL16(vbase + (size_t)d * MTOT + k0 + k8 * 8, &Vs[c * 8]);
        }

        // ---- S = Q K^T (both row-groups share kf reads) ----
        f32x4 s[2][4] = {{}};
#pragma unroll
        for (int j = 0; j < 4; ++j) {
            const int krow = j * 16 + lr;
#pragma unroll
            for (int c = 0; c < 4; ++c) {
                bf16x8 kf = *(const bf16x8*)&Ks[cur][krow * 128 + (((c * 4 + lg) ^ (krow & 7)) * 8)];
                s[0][j] = __builtin_amdgcn_mfma_f32_16x16x32_bf16(qf[0][c], kf, s[0][j], 0, 0, 0);
                s[1][j] = __builtin_amdgcn_mfma_f32_16x16x32_bf16(qf[1][c], kf, s[1][j], 0, 0, 0);
            }
        }

        // ---- scale + causal mask + online softmax ----
        float al[2][4];
#pragma unroll
        for (int rg = 0; rg < 2; ++rg) {
            const int qb0 = q_base + rg * 16;
#pragma unroll
            for (int j = 0; j < 4; ++j)
#pragma unroll
                for (int r = 0; r < 4; ++r) s[rg][j][r] *= sc;
            if (k0 + 63 > qb0) {
#pragma unroll
                for (int j = 0; j < 4; ++j) {
                    const int key = k0 + j * 16 + lr;
#pragma unroll
                    for (int r = 0; r < 4; ++r)
                        if (key > qb0 + lg * 4 + r) s[rg][j][r] = -3.0e38f;
                }
            }
#pragma unroll
            for (int r = 0; r < 4; ++r) {
                float tm = fmaxf(fmaxf(s[rg][0][r], s[rg][1][r]), fmaxf(s[rg][2][r], s[rg][3][r]));
                tm = fmaxf(tm, __shfl_xor(tm, 1));
                tm = fmaxf(tm, __shfl_xor(tm, 2));
                tm = fmaxf(tm, __shfl_xor(tm, 4));
                tm = fmaxf(tm, __shfl_xor(tm, 8));
                const float mn = fmaxf(m[rg][r], tm);
                const float a = __expf(m[rg][r] - mn);
                m[rg][r] = mn;
                float rs = 0.f;
#pragma unroll
                for (int j = 0; j < 4; ++j) { s[rg][j][r] = __expf(s[rg][j][r] - mn); rs += s[rg][j][r]; }
                rs += __shfl_xor(rs, 1); rs += __shfl_xor(rs, 2);
                rs += __shfl_xor(rs, 4); rs += __shfl_xor(rs, 8);
                lsum[rg][r] = lsum[rg][r] * a + rs;
                al[rg][r] = a;
            }
#pragma unroll
            for (int i = 0; i < 8; ++i)
#pragma unroll
                for (int r = 0; r < 4; ++r) o[rg][i][r] *= al[rg][r];
        }

        __syncthreads();   // barrier 1: V (+next K) landed; all Ks[cur] reads done

        // ---- P relayout (swizzled Ps, rg-sequential to halve buffer) ----
        bf16x8 pa[2][2];
#pragma unroll
        for (int rg = 0; rg < 2; ++rg) {
#pragma unroll
            for (int j = 0; j < 4; ++j) {
#pragma unroll
                for (int r = 0; r < 4; ++r) {
                    const int prow = lg * 4 + r;
                    const int chunk = (j * 2 + (lr >> 3)) ^ (prow & 7);
                    Ps[w][prow][chunk * 8 + (lr & 7)] = f2bf(s[rg][j][r]);
                }
            }
#pragma unroll
            for (int kc = 0; kc < 2; ++kc)
                pa[rg][kc] = *(const bf16x8*)&Ps[w][lr][((kc * 4 + lg) ^ (lr & 7)) * 8];
        }

        // ---- O += P V (vf reads shared across row-groups) ----
#pragma unroll
        for (int i = 0; i < 8; ++i) {
            const int d = i * 16 + lr;
#pragma unroll
            for (int kc = 0; kc < 2; ++kc) {
                bf16x8 vf = *(const bf16x8*)&Vs[d * 64 + (((kc * 4 + lg) ^ (d & 7)) * 8)];
                o[0][i] = __builtin_amdgcn_mfma_f32_16x16x32_bf16(pa[0][kc], vf, o[0][i], 0, 0, 0);
                o[1][i] = __builtin_amdgcn_mfma_f32_16x16x32_bf16(pa[1][kc], vf, o[1][i], 0, 0, 0);
            }
        }
        __syncthreads();   // barrier 2: all PV reads of Vs done before next stage
        cur ^= 1;
    }

    // ---- epilogue ----
#pragma unroll
    for (int rg = 0; rg < 2; ++rg) {
        float inv[4];
#pragma unroll
        for (int r = 0; r < 4; ++r) inv[r] = 1.f / lsum[rg][r];
#pragma unroll
        for (int i = 0; i < 8; ++i)
#pragma unroll
            for (int r = 0; r < 4; ++r)
                ob[(size_t)(b * T_SEQ + q_base + rg * 16 + lg * 4 + r) * DMODEL + h * DH + i * 16 + lr]
                    = f2bf(o[rg][i][r] * inv[r]);
    }
}

extern "C" void kernel_launch(void* const* d_in, const int* in_sizes, int n_in,
                              void* d_out, int out_size, void* d_ws, size_t ws_size,
                              hipStream_t stream) {
    const float* x      = (const float*)d_in[0];  // [4096, 2048]
    const float* wq     = (const float*)d_in[1];  // [2048, 2048]
    const float* w_down = (const float*)d_in[2];  // [2048, 1024]
    const float* w_up   = (const float*)d_in[3];  // [1024, 4096]
    const float* wo     = (const float*)d_in[4];  // [2048, 2048]
    float* out = (float*)d_out;

    uint8_t* p = (uint8_t*)d_ws;
    float* cosb = (float*)p;            p += (size_t)T_SEQ * 64 * 4;
    float* sinb = (float*)p;            p += (size_t)T_SEQ * 64 * 4;
    unsigned short* xb   = (unsigned short*)p; p += (size_t)MTOT * DMODEL * 2;
    unsigned short* wqT  = (unsigned short*)p; p += (size_t)DMODEL * DMODEL * 2;
    unsigned short* wdT  = (unsigned short*)p; p += (size_t)DLAT * DMODEL * 2;
    unsigned short* wuT  = (unsigned short*)p; p += (size_t)(2 * NH * DH) * DLAT * 2;
    unsigned short* woT  = (unsigned short*)p; p += (size_t)DMODEL * DMODEL * 2;
    unsigned short* qbuf = (unsigned short*)p; p += (size_t)MTOT * DMODEL * 2;
    unsigned short* ckv  = (unsigned short*)p; p += (size_t)MTOT * DLAT * 2;
    unsigned short* kbuf = (unsigned short*)p; p += (size_t)MTOT * DMODEL * 2;
    unsigned short* vbuf = (unsigned short*)p; p += (size_t)MTOT * DMODEL * 2;
    unsigned short* vT   = (unsigned short*)p; p += (size_t)DMODEL * MTOT * 2;
    unsigned short* abuf = xb;   // alias: xb dead after GEMM of c_kv, abuf written after

    // prep: tables + conversions/transposes
    rope_table_kernel<<<(T_SEQ * 64) / 256, 256, 0, stream>>>(cosb, sinb);
    conv_f2b_kernel<<<(MTOT * DMODEL / 4) / 256, 256, 0, stream>>>(x, xb);
    transpose_f2b_kernel<<<dim3(DMODEL / 32, DMODEL / 32), 256, 0, stream>>>(wq, wqT, DMODEL, DMODEL);
    transpose_f2b_kernel<<<dim3(DLAT / 32, DMODEL / 32), 256, 0, stream>>>(w_down, wdT, DMODEL, DLAT);
    transpose_f2b_kernel<<<dim3((2 * NH * DH) / 32, DLAT / 32), 256, 0, stream>>>(w_up, wuT, DLAT, 2 * NH * DH);
    transpose_f2b_kernel<<<dim3(DMODEL / 32, DMODEL / 32), 256, 0, stream>>>(wo, woT, DMODEL, DMODEL);

    // q = rope(x @ wq)
    gemm_bf16_kernel<1><<<dim3(DMODEL / 128, MTOT / 128), 256, 0, stream>>>(
        xb, wqT, qbuf, nullptr, cosb, sinb, MTOT, DMODEL, DMODEL);
    // c_kv = x @ w_down
    gemm_bf16_kernel<0><<<dim3(DLAT / 128, MTOT / 128), 256, 0, stream>>>(
        xb, wdT, ckv, nullptr, cosb, sinb, MTOT, DLAT, DMODEL);
    // kv_up = c_kv @ w_up -> k (rope) / v
    gemm_bf16_kernel<2><<<dim3((2 * NH * DH) / 128, MTOT / 128), 256, 0, stream>>>(
        ckv, wuT, kbuf, vbuf, cosb, sinb, MTOT, 2 * NH * DH, DLAT);
    // v -> v^T
    transpose_b2b_kernel<<<dim3(DMODEL / 32, MTOT / 32), 256, 0, stream>>>(vbuf, vT, MTOT, DMODEL);
    // attention (staged, LPT-ordered)
    attn_mfma2_kernel<<<dim3(BATCH * NH, 16), 256, 0, stream>>>(qbuf, kbuf, vT, abuf);
    // out = attn @ wo (fp32)
    gemm_bf16_kernel<3><<<dim3(DMODEL / 128, MTOT / 128), 256, 0, stream>>>(
        abuf, woT, out, nullptr, cosb, sinb, MTOT, DMODEL, DMODEL);
}

// Round 4
// 451.907 us; speedup vs baseline: 11.0672x; 1.1248x over previous
//
#include <hip/hip_runtime.h>
#include <math.h>
#include <stdint.h>

#define T_SEQ 2048
#define DMODEL 2048
#define DLAT 1024
#define NH 16
#define DH 128
#define BATCH 2
#define MTOT (BATCH * T_SEQ)   // 4096 rows total

typedef float f32x4 __attribute__((ext_vector_type(4)));
typedef __bf16 bf16x8 __attribute__((ext_vector_type(8)));

__device__ __forceinline__ unsigned short f2bf(float f) {
    return __builtin_bit_cast(unsigned short, (__bf16)f);   // RNE native cvt
}

#define EXP2F(x) __builtin_amdgcn_exp2f(x)

// 16-lane (row) reductions via DPP: quad_perm xor1, xor2, row_ror:4, row_ror:8
__device__ __forceinline__ float red16_max(float v) {
    int x = __builtin_bit_cast(int, v);
    v = fmaxf(v, __builtin_bit_cast(float, __builtin_amdgcn_update_dpp(x, x, 0xB1, 0xf, 0xf, false)));
    x = __builtin_bit_cast(int, v);
    v = fmaxf(v, __builtin_bit_cast(float, __builtin_amdgcn_update_dpp(x, x, 0x4E, 0xf, 0xf, false)));
    x = __builtin_bit_cast(int, v);
    v = fmaxf(v, __builtin_bit_cast(float, __builtin_amdgcn_update_dpp(x, x, 0x124, 0xf, 0xf, false)));
    x = __builtin_bit_cast(int, v);
    v = fmaxf(v, __builtin_bit_cast(float, __builtin_amdgcn_update_dpp(x, x, 0x128, 0xf, 0xf, false)));
    return v;
}
__device__ __forceinline__ float red16_sum(float v) {
    int x = __builtin_bit_cast(int, v);
    v += __builtin_bit_cast(float, __builtin_amdgcn_update_dpp(x, x, 0xB1, 0xf, 0xf, false));
    x = __builtin_bit_cast(int, v);
    v += __builtin_bit_cast(float, __builtin_amdgcn_update_dpp(x, x, 0x4E, 0xf, 0xf, false));
    x = __builtin_bit_cast(int, v);
    v += __builtin_bit_cast(float, __builtin_amdgcn_update_dpp(x, x, 0x124, 0xf, 0xf, false));
    x = __builtin_bit_cast(int, v);
    v += __builtin_bit_cast(float, __builtin_amdgcn_update_dpp(x, x, 0x128, 0xf, 0xf, false));
    return v;
}

// async global->LDS, 16B per lane (dest must be linear: wave base + lane*16)
#define GLL16(g, l) __builtin_amdgcn_global_load_lds( \
    (const __attribute__((address_space(1))) unsigned int*)(g), \
    (__attribute__((address_space(3))) unsigned int*)(l), 16, 0, 0)

// ---------------- RoPE tables: cos/sin [T][64] fp32 ----------------
__global__ void rope_table_kernel(float* __restrict__ cosb, float* __restrict__ sinb) {
    int idx = blockIdx.x * blockDim.x + threadIdx.x;
    if (idx >= T_SEQ * 64) return;
    int t = idx >> 6;
    int i = idx & 63;
    float inv = expf(-((2.0f * (float)i) / 128.0f) * logf(10000.0f));
    float ang = (float)t * inv;
    cosb[idx] = cosf(ang);
    sinb[idx] = sinf(ang);
}

// ---------------- fp32 -> bf16 elementwise (x) ----------------
__global__ void conv_f2b_kernel(const float* __restrict__ s, unsigned short* __restrict__ d) {
    int i = (blockIdx.x * blockDim.x + threadIdx.x) * 4;
    float4 v = *(const float4*)(s + i);
    ushort4 o;
    o.x = f2bf(v.x); o.y = f2bf(v.y); o.z = f2bf(v.z); o.w = f2bf(v.w);
    *(ushort4*)(d + i) = o;
}

// ---------------- fp32 [R][C] -> bf16 [C][R] transpose ----------------
__global__ void transpose_f2b_kernel(const float* __restrict__ src, unsigned short* __restrict__ dst,
                                     int R, int C) {
    __shared__ unsigned short tile[32][33];
    int tx = threadIdx.x & 31, ty = threadIdx.x >> 5;   // 32 x 8
    int r0 = blockIdx.y * 32, c0 = blockIdx.x * 32;
#pragma unroll
    for (int i = 0; i < 32; i += 8)
        tile[ty + i][tx] = f2bf(src[(size_t)(r0 + ty + i) * C + c0 + tx]);
    __syncthreads();
#pragma unroll
    for (int i = 0; i < 32; i += 8)
        dst[(size_t)(c0 + ty + i) * R + r0 + tx] = tile[tx][ty + i];
}

// ---------------- bf16 [R][C] -> bf16 [C][R] transpose (V -> V^T) ----------------
__global__ void transpose_b2b_kernel(const unsigned short* __restrict__ src, unsigned short* __restrict__ dst,
                                     int R, int C) {
    __shared__ unsigned short tile[32][33];
    int tx = threadIdx.x & 31, ty = threadIdx.x >> 5;
    int r0 = blockIdx.y * 32, c0 = blockIdx.x * 32;
#pragma unroll
    for (int i = 0; i < 32; i += 8)
        tile[ty + i][tx] = src[(size_t)(r0 + ty + i) * C + c0 + tx];
    __syncthreads();
#pragma unroll
    for (int i = 0; i < 32; i += 8)
        dst[(size_t)(c0 + ty + i) * R + r0 + tx] = tile[tx][ty + i];
}

// ---------------- bf16 MFMA GEMM: C[M,N] = A[M,K] * BT[N,K]^T ----------------
// 128x128 tile, BK=32, 256 thr (4 waves 2x2), wave = 64x64 = 4x4 frags of 16x16x32.
// EPI: 2 = K(RoPE)/V split bf16, 3 = fp32 store,
//      4 = fused q/ckv: col<2048 -> RoPE -> C0 (stride 2048); else -> C1 (stride 1024)
template <int EPI>
__global__ __launch_bounds__(256)
void gemm_bf16_kernel(const unsigned short* __restrict__ A, const unsigned short* __restrict__ BT,
                      void* __restrict__ C0, void* __restrict__ C1,
                      const float* __restrict__ cosb, const float* __restrict__ sinb,
                      int M, int N, int K) {
    __shared__ unsigned short As[128 * 32];
    __shared__ unsigned short Bs[128 * 32];
    const int t = threadIdx.x;
    const int w = t >> 6, l = t & 63;
    const int wr = w >> 1, wc = w & 1;
    const int lr = l & 15, lg = l >> 4;
    const int m0 = blockIdx.y * 128, n0 = blockIdx.x * 128;

    f32x4 acc[4][4] = {{}};

    const unsigned short* aP  = A  + (size_t)(m0 + (t >> 2)) * K + (t & 3) * 8;
    const unsigned short* aP2 = aP + (size_t)64 * K;
    const unsigned short* bP  = BT + (size_t)(n0 + (t >> 2)) * K + (t & 3) * 8;
    const unsigned short* bP2 = bP + (size_t)64 * K;

    for (int k0 = 0; k0 < K; k0 += 32) {
        __syncthreads();                       // protect previous iteration's reads
        GLL16(aP  + k0, &As[t * 8]);
        GLL16(aP2 + k0, &As[2048 + t * 8]);
        GLL16(bP  + k0, &Bs[t * 8]);
        GLL16(bP2 + k0, &Bs[2048 + t * 8]);
        __syncthreads();                       // drains vmcnt (loads landed)

        bf16x8 af[4], bfr[4];
#pragma unroll
        for (int i = 0; i < 4; ++i)
            af[i] = *(const bf16x8*)&As[(wr * 64 + i * 16 + lr) * 32 + lg * 8];
#pragma unroll
        for (int j = 0; j < 4; ++j)
            bfr[j] = *(const bf16x8*)&Bs[(wc * 64 + j * 16 + lr) * 32 + lg * 8];
#pragma unroll
        for (int i = 0; i < 4; ++i)
#pragma unroll
            for (int j = 0; j < 4; ++j)
                acc[i][j] = __builtin_amdgcn_mfma_f32_16x16x32_bf16(af[i], bfr[j], acc[i][j], 0, 0, 0);
    }

    const bool is_v  = (EPI == 2) && ((n0 & 128) != 0);    // block-uniform
    const bool is_cv = (EPI == 4) && (n0 >= 2048);         // fused: c_kv half
#pragma unroll
    for (int i = 0; i < 4; ++i) {
#pragma unroll
        for (int j = 0; j < 4; ++j) {
#pragma unroll
            for (int rr = 0; rr < 4; ++rr) {
                const int row_g = m0 + wr * 64 + i * 16 + lg * 4 + rr;
                const int col_g = n0 + wc * 64 + j * 16 + lr;
                float v = acc[i][j][rr];
                if (EPI == 2) {
                    float res = v;
                    if (!is_v) {  // K half -> RoPE
                        float o_ = __shfl_xor(v, 1);
                        int d = col_g & 127;
                        int tp = row_g & (T_SEQ - 1);
                        float c = cosb[tp * 64 + (d >> 1)];
                        float s = sinb[tp * 64 + (d >> 1)];
                        res = (lr & 1) ? (o_ * s + v * c) : (v * c - o_ * s);
                    }
                    int dcol = ((col_g >> 8) << 7) | (col_g & 127);  // head*128 + d
                    unsigned short* dst = is_v ? (unsigned short*)C1 : (unsigned short*)C0;
                    dst[(size_t)row_g * DMODEL + dcol] = f2bf(res);
                } else if (EPI == 3) {  // fp32 final
                    ((float*)C0)[(size_t)row_g * N + col_g] = v;
                } else {  // EPI == 4 fused q / c_kv
                    if (!is_cv) {       // q half -> RoPE -> C0 [.][2048]
                        float o_ = __shfl_xor(v, 1);
                        int d = col_g & 127;
                        int tp = row_g & (T_SEQ - 1);
                        float c = cosb[tp * 64 + (d >> 1)];
                        float s = sinb[tp * 64 + (d >> 1)];
                        float res = (lr & 1) ? (o_ * s + v * c) : (v * c - o_ * s);
                        ((unsigned short*)C0)[(size_t)row_g * DMODEL + col_g] = f2bf(res);
                    } else {            // c_kv -> C1 [.][1024]
                        ((unsigned short*)C1)[(size_t)row_g * DLAT + (col_g - 2048)] = f2bf(v);
                    }
                }
            }
        }
    }
}

// ---------------- staged bf16 MFMA causal flash attention ----------------
// grid (B*NH, 16), 256 thr = 4 waves. Block: 128 q-rows. KV tiles of 64 keys:
// K double-buffered LDS, V^T single (staged at iter top). XOR-swizzled LDS via
// pre-swizzled global_load_lds source. LPT: qt = 15 - blockIdx.y.
// Softmax in exp2 domain; defer-rescale (THR=8); DPP row reductions; setprio MFMA.
__global__ __launch_bounds__(256, 2)
void attn_mfma2_kernel(const unsigned short* __restrict__ qb, const unsigned short* __restrict__ kb,
                       const unsigned short* __restrict__ vT, unsigned short* __restrict__ ob) {
    __shared__ __align__(16) unsigned short Ks[2][64 * 128];   // 2 x 16KB
    __shared__ __align__(16) unsigned short Vs[128 * 64];      // 16KB (V^T: d-major)
    __shared__ __align__(16) unsigned short Ps[4][16][64];     // 8KB, per-wave P buf

    const int bh = blockIdx.x;
    const int b = bh >> 4, h = bh & 15;
    const int qt = 15 - blockIdx.y;           // longest blocks first
    const int t = threadIdx.x;
    const int w = t >> 6, l = t & 63;
    const int lr = l & 15, lg = l >> 4;

    const unsigned short* kbase = kb + (size_t)(b * T_SEQ) * DMODEL + h * DH;
    const unsigned short* vbase = vT + (size_t)(h * DH) * MTOT + (size_t)b * T_SEQ;
    const float sc2 = 0.08838834764831845f * 1.44269504089f;   // 1/sqrt(128) * log2(e)

    const int q0 = qt * 128;
    const int q_base = q0 + w * 32;

    // Q frags: rg in {0,1}, rows q_base + rg*16 + lr
    bf16x8 qf[2][4];
#pragma unroll
    for (int rg = 0; rg < 2; ++rg) {
        const unsigned short* qrow = qb + (size_t)(b * T_SEQ + q_base + rg * 16 + lr) * DMODEL + h * DH;
#pragma unroll
        for (int c = 0; c < 4; ++c) qf[rg][c] = *(const bf16x8*)(qrow + c * 32 + lg * 8);
    }

    f32x4 o[2][8] = {{}};
    float m[2][4], lsum[2][4];
#pragma unroll
    for (int rg = 0; rg < 2; ++rg)
#pragma unroll
        for (int r = 0; r < 4; ++r) { m[rg][r] = -3.0e38f; lsum[rg][r] = 0.f; }

    const int nt = 2 * qt + 2;
    int cur = 0;

    // prologue: stage K tile 0 into Ks[0] (src pre-swizzled, LDS dest linear)
#pragma unroll
    for (int i = 0; i < 4; ++i) {
        int c = i * 256 + t;                  // 16B chunk 0..1023
        int row = c >> 4;                     // 0..63
        int k16 = (c & 15) ^ (row & 7);
        GLL16(kbase + (size_t)row * DMODEL + k16 * 8, &Ks[0][c * 8]);
    }
    __syncthreads();

    for (int kt = 0; kt < nt; ++kt) {
        const int k0 = kt * 64;
        // prefetch next K tile into other buffer
        if (kt + 1 < nt) {
            const int kn = k0 + 64;
#pragma unroll
            for (int i = 0; i < 4; ++i) {
                int c = i * 256 + t;
                int row = c >> 4;
                int k16 = (c & 15) ^ (row & 7);
                GLL16(kbase + (size_t)(kn + row) * DMODEL + k16 * 8, &Ks[cur ^ 1][c * 8]);
            }
        }
        // stage current V^T tile (consumed after barrier 1)
#pragma unroll
        for (int i = 0; i < 4; ++i) {
            int c = i * 256 + t;              // 0..1023
            int d = c >> 3;                   // 0..127
            int k8 = (c & 7) ^ (d & 7);
            GLL16(vbase + (size_t)d * MTOT + k0 + k8 * 8, &Vs[c * 8]);
        }

        // ---- S = Q K^T (both row-groups share kf reads) ----
        f32x4 s[2][4] = {{}};
        __builtin_amdgcn_s_setprio(1);
#pragma unroll
        for (int j = 0; j < 4; ++j) {
            const int krow = j * 16 + lr;
#pragma unroll
            for (int c = 0; c < 4; ++c) {
                bf16x8 kf = *(const bf16x8*)&Ks[cur][krow * 128 + (((c * 4 + lg) ^ (krow & 7)) * 8)];
                s[0][j] = __builtin_amdgcn_mfma_f32_16x16x32_bf16(qf[0][c], kf, s[0][j], 0, 0, 0);
                s[1][j] = __builtin_amdgcn_mfma_f32_16x16x32_bf16(qf[1][c], kf, s[1][j], 0, 0, 0);
            }
        }
        __builtin_amdgcn_s_setprio(0);

        // ---- scale(log2) + causal mask + online softmax (defer-rescale) ----
#pragma unroll
        for (int rg = 0; rg < 2; ++rg) {
            const int qb0 = q_base + rg * 16;
#pragma unroll
            for (int j = 0; j < 4; ++j)
#pragma unroll
                for (int r = 0; r < 4; ++r) s[rg][j][r] *= sc2;
            if (k0 + 63 > qb0) {
#pragma unroll
                for (int j = 0; j < 4; ++j) {
                    const int key = k0 + j * 16 + lr;
#pragma unroll
                    for (int r = 0; r < 4; ++r)
                        if (key > qb0 + lg * 4 + r) s[rg][j][r] = -3.0e38f;
                }
            }
            float tm[4];
            int need = 0;
#pragma unroll
            for (int r = 0; r < 4; ++r) {
                float v = fmaxf(fmaxf(s[rg][0][r], s[rg][1][r]), fmaxf(s[rg][2][r], s[rg][3][r]));
                tm[r] = red16_max(v);
                need |= (tm[r] - m[rg][r] > 8.0f) ? 1 : 0;
            }
            if (__any(need)) {
#pragma unroll
                for (int r = 0; r < 4; ++r) {
                    const float mn = fmaxf(m[rg][r], tm[r]);
                    const float a = EXP2F(m[rg][r] - mn);
                    m[rg][r] = mn;
                    lsum[rg][r] *= a;
#pragma unroll
                    for (int i = 0; i < 8; ++i) o[rg][i][r] *= a;
                }
            }
#pragma unroll
            for (int r = 0; r < 4; ++r) {
                float rs = 0.f;
#pragma unroll
                for (int j = 0; j < 4; ++j) { s[rg][j][r] = EXP2F(s[rg][j][r] - m[rg][r]); rs += s[rg][j][r]; }
                lsum[rg][r] += red16_sum(rs);
            }
        }

        __syncthreads();   // barrier 1: V (+next K) landed; all Ks[cur] reads done

        // ---- P relayout (swizzled Ps, rg-sequential to halve buffer) ----
        bf16x8 pa[2][2];
#pragma unroll
        for (int rg = 0; rg < 2; ++rg) {
#pragma unroll
            for (int j = 0; j < 4; ++j) {
#pragma unroll
                for (int r = 0; r < 4; ++r) {
                    const int prow = lg * 4 + r;
                    const int chunk = (j * 2 + (lr >> 3)) ^ (prow & 7);
                    Ps[w][prow][chunk * 8 + (lr & 7)] = f2bf(s[rg][j][r]);
                }
            }
#pragma unroll
            for (int kc = 0; kc < 2; ++kc)
                pa[rg][kc] = *(const bf16x8*)&Ps[w][lr][((kc * 4 + lg) ^ (lr & 7)) * 8];
        }

        // ---- O += P V (vf reads shared across row-groups) ----
        __builtin_amdgcn_s_setprio(1);
#pragma unroll
        for (int i = 0; i < 8; ++i) {
            const int d = i * 16 + lr;
#pragma unroll
            for (int kc = 0; kc < 2; ++kc) {
                bf16x8 vf = *(const bf16x8*)&Vs[d * 64 + (((kc * 4 + lg) ^ (d & 7)) * 8)];
                o[0][i] = __builtin_amdgcn_mfma_f32_16x16x32_bf16(pa[0][kc], vf, o[0][i], 0, 0, 0);
                o[1][i] = __builtin_amdgcn_mfma_f32_16x16x32_bf16(pa[1][kc], vf, o[1][i], 0, 0, 0);
            }
        }
        __builtin_amdgcn_s_setprio(0);
        __syncthreads();   // barrier 2: all PV reads of Vs done before next stage
        cur ^= 1;
    }

    // ---- epilogue ----
#pragma unroll
    for (int rg = 0; rg < 2; ++rg) {
        float inv[4];
#pragma unroll
        for (int r = 0; r < 4; ++r) inv[r] = 1.f / lsum[rg][r];
#pragma unroll
        for (int i = 0; i < 8; ++i)
#pragma unroll
            for (int r = 0; r < 4; ++r)
                ob[(size_t)(b * T_SEQ + q_base + rg * 16 + lg * 4 + r) * DMODEL + h * DH + i * 16 + lr]
                    = f2bf(o[rg][i][r] * inv[r]);
    }
}

extern "C" void kernel_launch(void* const* d_in, const int* in_sizes, int n_in,
                              void* d_out, int out_size, void* d_ws, size_t ws_size,
                              hipStream_t stream) {
    const float* x      = (const float*)d_in[0];  // [4096, 2048]
    const float* wq     = (const float*)d_in[1];  // [2048, 2048]
    const float* w_down = (const float*)d_in[2];  // [2048, 1024]
    const float* w_up   = (const float*)d_in[3];  // [1024, 4096]
    const float* wo     = (const float*)d_in[4];  // [2048, 2048]
    float* out = (float*)d_out;

    uint8_t* p = (uint8_t*)d_ws;
    float* cosb = (float*)p;            p += (size_t)T_SEQ * 64 * 4;
    float* sinb = (float*)p;            p += (size_t)T_SEQ * 64 * 4;
    unsigned short* xb   = (unsigned short*)p; p += (size_t)MTOT * DMODEL * 2;
    unsigned short* wqT  = (unsigned short*)p; p += (size_t)DMODEL * DMODEL * 2;  // [2048][2048]
    unsigned short* wdT  = (unsigned short*)p; p += (size_t)DLAT * DMODEL * 2;    // [1024][2048], contiguous after wqT
    unsigned short* wuT  = (unsigned short*)p; p += (size_t)(2 * NH * DH) * DLAT * 2;
    unsigned short* woT  = (unsigned short*)p; p += (size_t)DMODEL * DMODEL * 2;
    unsigned short* qbuf = (unsigned short*)p; p += (size_t)MTOT * DMODEL * 2;
    unsigned short* ckv  = (unsigned short*)p; p += (size_t)MTOT * DLAT * 2;
    unsigned short* kbuf = (unsigned short*)p; p += (size_t)MTOT * DMODEL * 2;
    unsigned short* vbuf = (unsigned short*)p; p += (size_t)MTOT * DMODEL * 2;
    unsigned short* vT   = (unsigned short*)p; p += (size_t)DMODEL * MTOT * 2;
    unsigned short* abuf = xb;   // alias: xb dead after fused GEMM, abuf written after

    // prep: tables + conversions/transposes
    rope_table_kernel<<<(T_SEQ * 64) / 256, 256, 0, stream>>>(cosb, sinb);
    conv_f2b_kernel<<<(MTOT * DMODEL / 4) / 256, 256, 0, stream>>>(x, xb);
    transpose_f2b_kernel<<<dim3(DMODEL / 32, DMODEL / 32), 256, 0, stream>>>(wq, wqT, DMODEL, DMODEL);
    transpose_f2b_kernel<<<dim3(DLAT / 32, DMODEL / 32), 256, 0, stream>>>(w_down, wdT, DMODEL, DLAT);
    transpose_f2b_kernel<<<dim3((2 * NH * DH) / 32, DLAT / 32), 256, 0, stream>>>(w_up, wuT, DLAT, 2 * NH * DH);
    transpose_f2b_kernel<<<dim3(DMODEL / 32, DMODEL / 32), 256, 0, stream>>>(wo, woT, DMODEL, DMODEL);

    // fused: [q | c_kv] = x @ [wq | w_down]  (wqT/wdT contiguous -> BT [3072][2048])
    gemm_bf16_kernel<4><<<dim3((DMODEL + DLAT) / 128, MTOT / 128), 256, 0, stream>>>(
        xb, wqT, qbuf, ckv, cosb, sinb, MTOT, DMODEL + DLAT, DMODEL);
    // kv_up = c_kv @ w_up -> k (rope) / v
    gemm_bf16_kernel<2><<<dim3((2 * NH * DH) / 128, MTOT / 128), 256, 0, stream>>>(
        ckv, wuT, kbuf, vbuf, cosb, sinb, MTOT, 2 * NH * DH, DLAT);
    // v -> v^T
    transpose_b2b_kernel<<<dim3(DMODEL / 32, MTOT / 32), 256, 0, stream>>>(vbuf, vT, MTOT, DMODEL);
    // attention (staged, LPT-ordered)
    attn_mfma2_kernel<<<dim3(BATCH * NH, 16), 256, 0, stream>>>(qbuf, kbuf, vT, abuf);
    // out = attn @ wo (fp32)
    gemm_bf16_kernel<3><<<dim3(DMODEL / 128, MTOT / 128), 256, 0, stream>>>(
        abuf, woT, out, nullptr, cosb, sinb, MTOT, DMODEL, DMODEL);
}